// Round 7
// baseline (151.393 us; speedup 1.0000x reference)
//
#include <hip/hip_runtime.h>
#include <hip/hip_bf16.h>

typedef __attribute__((ext_vector_type(8))) short v8s;            // 8 x bf16 (4 VGPRs) MFMA A/B (K=32)
typedef __attribute__((ext_vector_type(4))) short v4s;            // 4 x bf16 (2 VGPRs) MFMA A/B (K=16)
typedef __attribute__((ext_vector_type(8))) unsigned short u16x8;
typedef __attribute__((ext_vector_type(4))) float v4f;            // MFMA C/D

#define MFMA16(a, b, c) __builtin_amdgcn_mfma_f32_16x16x32_bf16((a), (b), (c), 0, 0, 0)

// K=16 bf16 MFMA: A-frag k = quad*4+j matches the 16x16 C-layout row granularity,
// so an S^T C-layout register block is directly a PV A-fragment (no cross-lane ops).
#if __has_builtin(__builtin_amdgcn_mfma_f32_16x16x16_bf16)
#define MFMA16K16(a, b, c) __builtin_amdgcn_mfma_f32_16x16x16_bf16((a), (b), (c), 0, 0, 0)
#elif __has_builtin(__builtin_amdgcn_mfma_f32_16x16x16bf16_1k)
#define MFMA16K16(a, b, c) __builtin_amdgcn_mfma_f32_16x16x16bf16_1k((a), (b), (c), 0, 0, 0)
#else
static __device__ __forceinline__ v4f mfma16k16_asm(v4s a, v4s b, v4f c) {
  v4f d;
  asm("v_mfma_f32_16x16x16_bf16 %0, %1, %2, %3" : "=v"(d) : "v"(a), "v"(b), "v"(c));
  return d;
}
#define MFMA16K16(a, b, c) mfma16k16_asm((a), (b), (c))
#endif

// async global->LDS, 16B per lane; LDS dest = wave-uniform base + lane*16
#define GLL16(g, l)                                                        \
  __builtin_amdgcn_global_load_lds(                                        \
      (const __attribute__((address_space(1))) unsigned int*)(g),          \
      (__attribute__((address_space(3))) unsigned int*)(l), 16, 0, 0)

// native v_exp_f32 (libm exp2f is a multi-op software expansion)
#if __has_builtin(__builtin_amdgcn_exp2f)
__device__ __forceinline__ float exp2n(float x) { return __builtin_amdgcn_exp2f(x); }
#else
__device__ __forceinline__ float exp2n(float x) {
  float r; asm("v_exp_f32 %0, %1" : "=v"(r) : "v"(x)); return r;
}
#endif

__device__ __forceinline__ unsigned short f2bf(float f) {
  union { float f; unsigned u; } v; v.f = f;
  unsigned r = v.u + 0x7fffu + ((v.u >> 16) & 1u);   // RNE
  return (unsigned short)(r >> 16);
}
// truncating pack of two f32 -> bf16x2 (lo in low half)
__device__ __forceinline__ unsigned packbf2(float lo, float hi) {
  union { float f; unsigned u; } a, b; a.f = lo; b.f = hi;
  return (a.u >> 16) | (b.u & 0xffff0000u);
}

// ---------------- fused: weight fp32->bf16 convert  +  GroupNorm stats ----------------
// blocks [0, 1024): convert qkv_w then proj_w (256 float4 each)
// blocks [1024, 1280): gn stats, one block per (b, group) -> (mu, rsig)
__global__ __launch_bounds__(256) void cvt_gn_kernel(const float* __restrict__ in0,
                                                     unsigned short* __restrict__ out0,
                                                     const float* __restrict__ in1,
                                                     unsigned short* __restrict__ out1,
                                                     int n0, int n1,
                                                     const float* __restrict__ x,
                                                     float2* __restrict__ stats) {
  if (blockIdx.x < 1024) {
    int i = blockIdx.x * 256 + threadIdx.x;
    const float* in; unsigned short* out;
    if (i < n0) { in = in0; out = out0; }
    else        { i -= n0; if (i >= n1) return; in = in1; out = out1; }
    float4 v = ((const float4*)in)[i];
    ushort4 o;
    o.x = f2bf(v.x); o.y = f2bf(v.y); o.z = f2bf(v.z); o.w = f2bf(v.w);
    ((ushort4*)out)[i] = o;
    return;
  }
  const int bg = blockIdx.x - 1024;            // 0..255
  const float4* xp4 = (const float4*)(x + (size_t)bg * 16 * 1024);
  float s = 0.f, ss = 0.f;
  for (int i = threadIdx.x; i < 4096; i += 256) {
    float4 v = xp4[i];
    s  += (v.x + v.y) + (v.z + v.w);
    ss += (v.x * v.x + v.y * v.y) + (v.z * v.z + v.w * v.w);
  }
  #pragma unroll
  for (int d = 1; d < 64; d <<= 1) { s += __shfl_xor(s, d); ss += __shfl_xor(ss, d); }
  __shared__ float red[2][4];
  const int w = threadIdx.x >> 6;
  if ((threadIdx.x & 63) == 0) { red[0][w] = s; red[1][w] = ss; }
  __syncthreads();
  if (threadIdx.x == 0) {
    s  = red[0][0] + red[0][1] + red[0][2] + red[0][3];
    ss = red[1][0] + red[1][1] + red[1][2] + red[1][3];
    const float mu  = s * (1.f / 16384.f);
    const float var = ss * (1.f / 16384.f) - mu * mu;
    stats[bg] = make_float2(mu, rsqrtf(var + 1e-5f));
  }
}

// ---------------- GroupNorm normalize + transpose: x[b][c][l] -> xnT[b][l][c] bf16 ----
__global__ __launch_bounds__(256) void gnt_kernel(const float* __restrict__ x,
                                                  const float2* __restrict__ stats,
                                                  const float* __restrict__ gsc,
                                                  const float* __restrict__ gbi,
                                                  unsigned short* __restrict__ xnT) {
  const int b = blockIdx.z, l0 = blockIdx.x * 64, c0 = blockIdx.y * 64;
  const float* sp = x + (size_t)b * 512 * 1024;
  unsigned short* dp = xnT + (size_t)b * 1024 * 512;
  __shared__ unsigned T[64][65];
  const int tid = threadIdx.x;
  const int rr = tid >> 3, c8 = (tid & 7) * 8;
  #pragma unroll
  for (int sw = 0; sw < 2; ++sw) {
    const int c = c0 + sw * 32 + rr;
    const float2 st = stats[b * 32 + (c >> 4)];
    const float sc = gsc[c] * st.y;
    const float bi = gbi[c] - st.x * sc;
    const float4* px = (const float4*)(sp + (size_t)c * 1024 + l0 + c8);
    float4 v0 = px[0], v1 = px[1];
    T[sw * 32 + rr][c8 + 0] = f2bf(v0.x * sc + bi);
    T[sw * 32 + rr][c8 + 1] = f2bf(v0.y * sc + bi);
    T[sw * 32 + rr][c8 + 2] = f2bf(v0.z * sc + bi);
    T[sw * 32 + rr][c8 + 3] = f2bf(v0.w * sc + bi);
    T[sw * 32 + rr][c8 + 4] = f2bf(v1.x * sc + bi);
    T[sw * 32 + rr][c8 + 5] = f2bf(v1.y * sc + bi);
    T[sw * 32 + rr][c8 + 6] = f2bf(v1.z * sc + bi);
    T[sw * 32 + rr][c8 + 7] = f2bf(v1.w * sc + bi);
  }
  __syncthreads();
  #pragma unroll
  for (int sw = 0; sw < 2; ++sw) {
    const int ll = sw * 32 + rr;
    u16x8 o;
    #pragma unroll
    for (int j = 0; j < 8; ++j) o[j] = (unsigned short)T[c8 + j][ll];
    *(u16x8*)(dp + (size_t)(l0 + ll) * 512 + c0 + c8) = o;
  }
}

// ---------------- 128xNT MFMA GEMM, BK=64, xor-swizzled 128B LDS rows ----------------
// A: [M][512] bf16 row-major. BT: [batch][1024][512] bf16 ([n][k]).
template <bool QKV, int NT>
__global__ __launch_bounds__(256) void gemm_kernel(
    const unsigned short* __restrict__ A,
    const unsigned short* __restrict__ BT,
    const float* __restrict__ bias,
    const float* __restrict__ xres,
    float* __restrict__ outf,
    unsigned short* __restrict__ qT,
    unsigned short* __restrict__ kT,
    unsigned short* __restrict__ vO) {
  constexpr int K = 512;
  constexpr int NFR = NT / 32;              // n-frags per wave
  constexpr int NJOB = 16 + NT / 8;         // staging jobs (A:16, B:NT/8)
  const int n0 = blockIdx.x * NT, m0 = blockIdx.y * 128, b = blockIdx.z;
  const unsigned short* Bp = BT + (size_t)b * 1024 * K;

  __shared__ __align__(16) unsigned short As[128][64];
  __shared__ __align__(16) unsigned short Bs[NT][64];

  const int tid = threadIdx.x, lane = tid & 63, w = tid >> 6;
  const int quad = lane >> 4, l15 = lane & 15;
  const int wm = (w >> 1) * 64, wn = (w & 1) * (NT / 2);
  const int srow = lane >> 3;
  const int scol = ((lane & 7) ^ srow) * 8;
  const int ck0 = ((quad ^ (l15 & 7)) * 8);
  const int ck1 = ck0 ^ 32;
  const unsigned short* Asf = &As[0][0];
  const unsigned short* Bsf = &Bs[0][0];

  v4f acc[4][NFR];
  #pragma unroll
  for (int i = 0; i < 4; ++i)
    #pragma unroll
    for (int j = 0; j < NFR; ++j) acc[i][j] = (v4f){0.f, 0.f, 0.f, 0.f};

  for (int kk = 0; kk < K; kk += 64) {
    __syncthreads();
    #pragma unroll
    for (int jj = 0; jj < NJOB / 4; ++jj) {
      const int job = w * (NJOB / 4) + jj;
      if (job < 16) {
        GLL16(A + (size_t)(m0 + job * 8 + srow) * K + kk + scol, &As[job * 8][0]);
      } else {
        const int j2 = job - 16;
        GLL16(Bp + (size_t)(n0 + j2 * 8 + srow) * K + kk + scol, &Bs[j2 * 8][0]);
      }
    }
    __syncthreads();
    #pragma unroll
    for (int h = 0; h < 2; ++h) {
      const int ck = h ? ck1 : ck0;
      v8s af[4], bf[NFR];
      #pragma unroll
      for (int mt = 0; mt < 4; ++mt) af[mt] = *(const v8s*)(Asf + (wm + mt * 16 + l15) * 64 + ck);
      #pragma unroll
      for (int nt = 0; nt < NFR; ++nt) bf[nt] = *(const v8s*)(Bsf + (wn + nt * 16 + l15) * 64 + ck);
      #pragma unroll
      for (int mt = 0; mt < 4; ++mt)
        #pragma unroll
        for (int nt = 0; nt < NFR; ++nt)
          acc[mt][nt] = MFMA16(af[mt], bf[nt], acc[mt][nt]);
    }
  }

  if (QKV) {
    const int bh8 = b * 8;
    const float cs = 0.18033688011112042f;   // 0.125 * log2(e), folded into q
    #pragma unroll
    for (int mt = 0; mt < 4; ++mt) {
      const int m4 = m0 + wm + mt * 16 + quad * 4;
      const int h = m4 / 192;
      const int rr = m4 - h * 192;
      const int part = rr >> 6;                          // 0=q 1=k 2=v
      const int ch = rr & 63;
      const float b0 = bias[m4], b1 = bias[m4 + 1], b2 = bias[m4 + 2], b3 = bias[m4 + 3];
      #pragma unroll
      for (int nt = 0; nt < NFR; ++nt) {
        const int n = n0 + wn + nt * 16 + l15;
        v4f a = acc[mt][nt];
        const float v0 = a[0] + b0, v1 = a[1] + b1, v2 = a[2] + b2, v3 = a[3] + b3;
        if (part == 0) {
          ushort4 st4;
          st4.x = f2bf(v0 * cs); st4.y = f2bf(v1 * cs);
          st4.z = f2bf(v2 * cs); st4.w = f2bf(v3 * cs);
          *(ushort4*)(qT + ((size_t)(bh8 + h) * 1024 + n) * 64 + ch) = st4;
        } else if (part == 1) {
          ushort4 st4;
          st4.x = f2bf(v0); st4.y = f2bf(v1); st4.z = f2bf(v2); st4.w = f2bf(v3);
          *(ushort4*)(kT + ((size_t)(bh8 + h) * 1024 + n) * 64 + ch) = st4;
        } else {
          unsigned short* dp = vO + ((size_t)(bh8 + h) * 64 + ch) * 1024 + n;
          dp[0] = f2bf(v0); dp[1024] = f2bf(v1); dp[2048] = f2bf(v2); dp[3072] = f2bf(v3);
        }
      }
    }
  } else {
    #pragma unroll
    for (int mt = 0; mt < 4; ++mt) {
      const int m4 = m0 + wm + mt * 16 + quad * 4;
      const float b0 = bias[m4], b1 = bias[m4 + 1], b2 = bias[m4 + 2], b3 = bias[m4 + 3];
      #pragma unroll
      for (int nt = 0; nt < NFR; ++nt) {
        const int n = n0 + wn + nt * 16 + l15;
        const size_t i0 = ((size_t)b * 512 + m4) * 1024 + n;
        outf[i0]        = xres[i0]        + acc[mt][nt][0] + b0;
        outf[i0 + 1024] = xres[i0 + 1024] + acc[mt][nt][1] + b1;
        outf[i0 + 2048] = xres[i0 + 2048] + acc[mt][nt][2] + b2;
        outf[i0 + 3072] = xres[i0 + 3072] + acc[mt][nt][3] + b3;
      }
    }
  }
}

// ---------------- Flash attention: 2-wave blocks, 64q/block, 32 q/wave --------------
// qT/kT: [bh][1024][64] bf16 (q pre-scaled by 0.125*log2e); v: [bh][64][1024] bf16.
// grid = (bh, t-tile): ID = bh + 64*t -> t-blocks of a head share an XCD (L2 K/V reuse).
// 32 KB LDS (Q staged through Ks[0]) -> 4 blocks/CU: 4 independent 2-wave barrier
// domains per CU hide each other's vmcnt-drain at __syncthreads.
__global__ __launch_bounds__(128) void attn_kernel(const unsigned short* __restrict__ qT,
                                                   const unsigned short* __restrict__ kT,
                                                   const unsigned short* __restrict__ vv,
                                                   unsigned short* __restrict__ aT) {
  const int bh = blockIdx.x;
  const int t0 = blockIdx.y * 64;
  const unsigned short* qb = qT + (size_t)bh * 1024 * 64;
  const unsigned short* kb = kT + (size_t)bh * 1024 * 64;
  const unsigned short* vb = vv + (size_t)bh * 64 * 1024;

  __shared__ __align__(16) unsigned short Ks[2][64][64];   // 16KB [buf][s][k]
  __shared__ __align__(16) unsigned short Vs[2][64][64];   // 16KB [buf][c][s]

  const int tid = threadIdx.x, w = tid >> 6, lane = tid & 63;
  const int quad = lane >> 4, l15 = lane & 15;
  const int srow = lane >> 3;
  const int scol = ((lane & 7) ^ srow) * 8;
  const int ck0 = ((quad ^ (l15 & 7)) * 8);
  const int ck1 = ck0 ^ 32;

  // ---- stage Q (64 rows) through Ks[0], read frags, then release the buffer ----
  #pragma unroll
  for (int jj = 0; jj < 4; ++jj) {
    const int seg = w * 4 + jj;              // 8 segs of 8 rows
    GLL16(qb + (size_t)(t0 + seg * 8 + srow) * 64 + scol, &Ks[0][seg * 8][0]);
  }
  __syncthreads();
  v8s qf[2][2];
  #pragma unroll
  for (int tg = 0; tg < 2; ++tg) {
    qf[tg][0] = *(const v8s*)(&Ks[0][0][0] + (w * 32 + tg * 16 + l15) * 64 + ck0);
    qf[tg][1] = *(const v8s*)(&Ks[0][0][0] + (w * 32 + tg * 16 + l15) * 64 + ck1);
  }
  __syncthreads();   // all waves done reading Q before Ks[0] is overwritten

  // ---- stage K/V tile 0: wave 0 -> K segs, wave 1 -> V segs (8 jobs each) ----
  #pragma unroll
  for (int jj = 0; jj < 8; ++jj) {
    const int j = w * 8 + jj;
    if (j < 8) GLL16(kb + (size_t)(j * 8 + srow) * 64 + scol, &Ks[0][j * 8][0]);
    else       GLL16(vb + (size_t)((j - 8) * 8 + srow) * 1024 + scol, &Vs[0][(j - 8) * 8][0]);
  }

  v4f o[2][4];
  #pragma unroll
  for (int tg = 0; tg < 2; ++tg)
    #pragma unroll
    for (int i = 0; i < 4; ++i) o[tg][i] = (v4f){0.f, 0.f, 0.f, 0.f};
  float lsum[2] = {0.f, 0.f};

  // V B-frag (16x16x16) address pieces: row = nc*16+l15, s = st*16 + quad*4 + i
  const int vq4 = (quad & 1) * 4;          // within-chunk short offset
  const int vqh = quad >> 1;               // chunk parity from quad

  for (int it = 0; it < 16; ++it) {
    __syncthreads();          // tile(it) resident (drains prefetch in flight)
    // prefetch next tile before compute of this one
    if (it + 1 < 16) {
      const int s1 = (it + 1) * 64, bp1 = (it + 1) & 1;
      #pragma unroll
      for (int jj = 0; jj < 8; ++jj) {
        const int j = w * 8 + jj;
        if (j < 8)
          GLL16(kb + (size_t)(s1 + j * 8 + srow) * 64 + scol, &Ks[bp1][j * 8][0]);
        else
          GLL16(vb + (size_t)((j - 8) * 8 + srow) * 1024 + s1 + scol,
                &Vs[bp1][(j - 8) * 8][0]);
      }
    }
    const unsigned short* Kb = &Ks[it & 1][0][0];
    const unsigned short* Vb = &Vs[it & 1][0][0];

    // S^T(64s x 32t) = K * Q^T ; sa[tg][st]: rows s = st*16+quad*4+r, col t = l15
    v4f sa[2][4];
    #pragma unroll
    for (int st = 0; st < 4; ++st) {
      v8s k0 = *(const v8s*)(Kb + (st * 16 + l15) * 64 + ck0);
      v8s k1 = *(const v8s*)(Kb + (st * 16 + l15) * 64 + ck1);
      #pragma unroll
      for (int tg = 0; tg < 2; ++tg) {
        v4f z = (v4f){0.f, 0.f, 0.f, 0.f};
        z = MFMA16(k0, qf[tg][0], z);
        sa[tg][st] = MFMA16(k1, qf[tg][1], z);
      }
    }

    // softmax without max subtraction (scores bounded; scale folded into q).
    // P stays in C-layout => directly the K=16 A-fragment.
    union { v4s v; unsigned u[2]; } pa[2][4];
    #pragma unroll
    for (int tg = 0; tg < 2; ++tg) {
      float rsum = 0.f;
      #pragma unroll
      for (int st = 0; st < 4; ++st) {
        float p0 = exp2n(sa[tg][st][0]);
        float p1 = exp2n(sa[tg][st][1]);
        float p2 = exp2n(sa[tg][st][2]);
        float p3 = exp2n(sa[tg][st][3]);
        rsum += (p0 + p1) + (p2 + p3);
        pa[tg][st].u[0] = packbf2(p0, p1);
        pa[tg][st].u[1] = packbf2(p2, p3);
      }
      lsum[tg] += rsum;
    }

    // O(32t x 64c) += P * V ; B-frag: V[s=st*16+quad*4+i][c=nc*16+l15] via ds_read_b64
    #pragma unroll
    for (int nc = 0; nc < 4; ++nc) {
      const int row = nc * 16 + l15;
      const unsigned short* vrow = Vb + row * 64 + vq4;
      const int rx = row & 7;
      #pragma unroll
      for (int st = 0; st < 4; ++st) {
        v4s vb4 = *(const v4s*)(vrow + ((st * 2 + vqh) ^ rx) * 8);
        o[0][nc] = MFMA16K16(pa[0][st].v, vb4, o[0][nc]);
        o[1][nc] = MFMA16K16(pa[1][st].v, vb4, o[1][nc]);
      }
    }
  }

  // final l reduce across quads; write aT[b][t][h*64+c] = O[t][c] / l(t)
  const int b = bh >> 3, h = bh & 7;
  #pragma unroll
  for (int tg = 0; tg < 2; ++tg) {
    lsum[tg] += __shfl_xor(lsum[tg], 16);
    lsum[tg] += __shfl_xor(lsum[tg], 32);
  }
  #pragma unroll
  for (int tg = 0; tg < 2; ++tg) {
    float rl[4];
    #pragma unroll
    for (int r = 0; r < 4; ++r) rl[r] = 1.0f / __shfl(lsum[tg], quad * 4 + r);
    #pragma unroll
    for (int nc = 0; nc < 4; ++nc)
      #pragma unroll
      for (int r = 0; r < 4; ++r) {
        aT[((size_t)b * 1024 + t0 + w * 32 + tg * 16 + quad * 4 + r) * 512 +
           h * 64 + nc * 16 + l15] = f2bf(o[tg][nc][r] * rl[r]);
      }
  }
}

extern "C" void kernel_launch(void* const* d_in, const int* in_sizes, int n_in,
                              void* d_out, int out_size, void* d_ws, size_t ws_size,
                              hipStream_t stream) {
  const float* x    = (const float*)d_in[0];
  const float* gsc  = (const float*)d_in[1];
  const float* gbi  = (const float*)d_in[2];
  const float* qkvw = (const float*)d_in[3];
  const float* qkvb = (const float*)d_in[4];
  const float* pjw  = (const float*)d_in[5];
  const float* pjb  = (const float*)d_in[6];
  float* out = (float*)d_out;

  unsigned short* ws  = (unsigned short*)d_ws;
  unsigned short* qw  = ws;                   //  786432  qkv weights bf16
  unsigned short* pw  = qw + 786432;          //  262144  proj weights bf16
  float2* stats = (float2*)(pw + 262144);     //  256 float2 = 1024 shorts
  unsigned short* xnT = pw + 262144 + 1024;   // 4194304  [b][l][c]
  unsigned short* qT  = xnT + 4194304;        // 4194304  [bh][l][64]
  unsigned short* kT  = qT + 4194304;         // 4194304  [bh][l][64]
  unsigned short* vv  = kT + 4194304;         // 4194304  [bh][64][l]
  unsigned short* aT  = vv + 4194304;         // 4194304  [b][l][c]
  // total ~44.04 MB

  cvt_gn_kernel<<<dim3(1280), dim3(256), 0, stream>>>(qkvw, qw, pjw, pw, 196608, 65536,
                                                      x, stats);
  gnt_kernel<<<dim3(16, 8, 8), dim3(256), 0, stream>>>(x, stats, gsc, gbi, xnT);
  gemm_kernel<true, 128><<<dim3(8, 12, 8), dim3(256), 0, stream>>>(
      qw, xnT, qkvb, nullptr, nullptr, qT, kT, vv);
  attn_kernel<<<dim3(64, 16), dim3(128), 0, stream>>>(qT, kT, vv, aT);
  gemm_kernel<false, 64><<<dim3(16, 4, 8), dim3(256), 0, stream>>>(
      pw, aT, pjb, x, out, nullptr, nullptr, nullptr);
}

// Round 8
// 149.290 us; speedup vs baseline: 1.0141x; 1.0141x over previous
//
#include <hip/hip_runtime.h>
#include <hip/hip_bf16.h>

typedef __attribute__((ext_vector_type(8))) short v8s;            // 8 x bf16 (4 VGPRs) MFMA A/B (K=32)
typedef __attribute__((ext_vector_type(4))) short v4s;            // 4 x bf16 (2 VGPRs) MFMA A/B (K=16)
typedef __attribute__((ext_vector_type(8))) unsigned short u16x8;
typedef __attribute__((ext_vector_type(4))) float v4f;            // MFMA C/D

#define MFMA16(a, b, c) __builtin_amdgcn_mfma_f32_16x16x32_bf16((a), (b), (c), 0, 0, 0)

// K=16 bf16 MFMA: A-frag k = quad*4+j matches the 16x16 C-layout row granularity,
// so an S^T C-layout register block is directly a PV A-fragment (no cross-lane ops).
#if __has_builtin(__builtin_amdgcn_mfma_f32_16x16x16_bf16)
#define MFMA16K16(a, b, c) __builtin_amdgcn_mfma_f32_16x16x16_bf16((a), (b), (c), 0, 0, 0)
#elif __has_builtin(__builtin_amdgcn_mfma_f32_16x16x16bf16_1k)
#define MFMA16K16(a, b, c) __builtin_amdgcn_mfma_f32_16x16x16bf16_1k((a), (b), (c), 0, 0, 0)
#else
static __device__ __forceinline__ v4f mfma16k16_asm(v4s a, v4s b, v4f c) {
  v4f d;
  asm("v_mfma_f32_16x16x16_bf16 %0, %1, %2, %3" : "=v"(d) : "v"(a), "v"(b), "v"(c));
  return d;
}
#define MFMA16K16(a, b, c) mfma16k16_asm((a), (b), (c))
#endif

// async global->LDS, 16B per lane; LDS dest = wave-uniform base + lane*16
#define GLL16(g, l)                                                        \
  __builtin_amdgcn_global_load_lds(                                        \
      (const __attribute__((address_space(1))) unsigned int*)(g),          \
      (__attribute__((address_space(3))) unsigned int*)(l), 16, 0, 0)

// native v_exp_f32 (libm exp2f is a multi-op software expansion)
#if __has_builtin(__builtin_amdgcn_exp2f)
__device__ __forceinline__ float exp2n(float x) { return __builtin_amdgcn_exp2f(x); }
#else
__device__ __forceinline__ float exp2n(float x) {
  float r; asm("v_exp_f32 %0, %1" : "=v"(r) : "v"(x)); return r;
}
#endif

__device__ __forceinline__ unsigned short f2bf(float f) {
  union { float f; unsigned u; } v; v.f = f;
  unsigned r = v.u + 0x7fffu + ((v.u >> 16) & 1u);   // RNE
  return (unsigned short)(r >> 16);
}
// truncating pack of two f32 -> bf16x2 (lo in low half)
__device__ __forceinline__ unsigned packbf2(float lo, float hi) {
  union { float f; unsigned u; } a, b; a.f = lo; b.f = hi;
  return (a.u >> 16) | (b.u & 0xffff0000u);
}

// ---------------- fused: weight fp32->bf16 convert  +  GroupNorm stats ----------------
__global__ __launch_bounds__(256) void cvt_gn_kernel(const float* __restrict__ in0,
                                                     unsigned short* __restrict__ out0,
                                                     const float* __restrict__ in1,
                                                     unsigned short* __restrict__ out1,
                                                     int n0, int n1,
                                                     const float* __restrict__ x,
                                                     float2* __restrict__ stats) {
  if (blockIdx.x < 1024) {
    int i = blockIdx.x * 256 + threadIdx.x;
    const float* in; unsigned short* out;
    if (i < n0) { in = in0; out = out0; }
    else        { i -= n0; if (i >= n1) return; in = in1; out = out1; }
    float4 v = ((const float4*)in)[i];
    ushort4 o;
    o.x = f2bf(v.x); o.y = f2bf(v.y); o.z = f2bf(v.z); o.w = f2bf(v.w);
    ((ushort4*)out)[i] = o;
    return;
  }
  const int bg = blockIdx.x - 1024;            // 0..255
  const float4* xp4 = (const float4*)(x + (size_t)bg * 16 * 1024);
  float s = 0.f, ss = 0.f;
  for (int i = threadIdx.x; i < 4096; i += 256) {
    float4 v = xp4[i];
    s  += (v.x + v.y) + (v.z + v.w);
    ss += (v.x * v.x + v.y * v.y) + (v.z * v.z + v.w * v.w);
  }
  #pragma unroll
  for (int d = 1; d < 64; d <<= 1) { s += __shfl_xor(s, d); ss += __shfl_xor(ss, d); }
  __shared__ float red[2][4];
  const int w = threadIdx.x >> 6;
  if ((threadIdx.x & 63) == 0) { red[0][w] = s; red[1][w] = ss; }
  __syncthreads();
  if (threadIdx.x == 0) {
    s  = red[0][0] + red[0][1] + red[0][2] + red[0][3];
    ss = red[1][0] + red[1][1] + red[1][2] + red[1][3];
    const float mu  = s * (1.f / 16384.f);
    const float var = ss * (1.f / 16384.f) - mu * mu;
    stats[bg] = make_float2(mu, rsqrtf(var + 1e-5f));
  }
}

// ---------------- GroupNorm normalize + transpose: x[b][c][l] -> xnT[b][l][c] bf16 ----
__global__ __launch_bounds__(256) void gnt_kernel(const float* __restrict__ x,
                                                  const float2* __restrict__ stats,
                                                  const float* __restrict__ gsc,
                                                  const float* __restrict__ gbi,
                                                  unsigned short* __restrict__ xnT) {
  const int b = blockIdx.z, l0 = blockIdx.x * 64, c0 = blockIdx.y * 64;
  const float* sp = x + (size_t)b * 512 * 1024;
  unsigned short* dp = xnT + (size_t)b * 1024 * 512;
  __shared__ unsigned T[64][65];
  const int tid = threadIdx.x;
  const int rr = tid >> 3, c8 = (tid & 7) * 8;
  #pragma unroll
  for (int sw = 0; sw < 2; ++sw) {
    const int c = c0 + sw * 32 + rr;
    const float2 st = stats[b * 32 + (c >> 4)];
    const float sc = gsc[c] * st.y;
    const float bi = gbi[c] - st.x * sc;
    const float4* px = (const float4*)(sp + (size_t)c * 1024 + l0 + c8);
    float4 v0 = px[0], v1 = px[1];
    T[sw * 32 + rr][c8 + 0] = f2bf(v0.x * sc + bi);
    T[sw * 32 + rr][c8 + 1] = f2bf(v0.y * sc + bi);
    T[sw * 32 + rr][c8 + 2] = f2bf(v0.z * sc + bi);
    T[sw * 32 + rr][c8 + 3] = f2bf(v0.w * sc + bi);
    T[sw * 32 + rr][c8 + 4] = f2bf(v1.x * sc + bi);
    T[sw * 32 + rr][c8 + 5] = f2bf(v1.y * sc + bi);
    T[sw * 32 + rr][c8 + 6] = f2bf(v1.z * sc + bi);
    T[sw * 32 + rr][c8 + 7] = f2bf(v1.w * sc + bi);
  }
  __syncthreads();
  #pragma unroll
  for (int sw = 0; sw < 2; ++sw) {
    const int ll = sw * 32 + rr;
    u16x8 o;
    #pragma unroll
    for (int j = 0; j < 8; ++j) o[j] = (unsigned short)T[c8 + j][ll];
    *(u16x8*)(dp + (size_t)(l0 + ll) * 512 + c0 + c8) = o;
  }
}

// ---------------- 128xNT MFMA GEMM, BK=64, xor-swizzled 128B LDS rows ----------------
template <bool QKV, int NT>
__global__ __launch_bounds__(256) void gemm_kernel(
    const unsigned short* __restrict__ A,
    const unsigned short* __restrict__ BT,
    const float* __restrict__ bias,
    const float* __restrict__ xres,
    float* __restrict__ outf,
    unsigned short* __restrict__ qT,
    unsigned short* __restrict__ kT,
    unsigned short* __restrict__ vO) {
  constexpr int K = 512;
  constexpr int NFR = NT / 32;              // n-frags per wave
  constexpr int NJOB = 16 + NT / 8;         // staging jobs (A:16, B:NT/8)
  const int n0 = blockIdx.x * NT, m0 = blockIdx.y * 128, b = blockIdx.z;
  const unsigned short* Bp = BT + (size_t)b * 1024 * K;

  __shared__ __align__(16) unsigned short As[128][64];
  __shared__ __align__(16) unsigned short Bs[NT][64];

  const int tid = threadIdx.x, lane = tid & 63, w = tid >> 6;
  const int quad = lane >> 4, l15 = lane & 15;
  const int wm = (w >> 1) * 64, wn = (w & 1) * (NT / 2);
  const int srow = lane >> 3;
  const int scol = ((lane & 7) ^ srow) * 8;
  const int ck0 = ((quad ^ (l15 & 7)) * 8);
  const int ck1 = ck0 ^ 32;
  const unsigned short* Asf = &As[0][0];
  const unsigned short* Bsf = &Bs[0][0];

  v4f acc[4][NFR];
  #pragma unroll
  for (int i = 0; i < 4; ++i)
    #pragma unroll
    for (int j = 0; j < NFR; ++j) acc[i][j] = (v4f){0.f, 0.f, 0.f, 0.f};

  for (int kk = 0; kk < K; kk += 64) {
    __syncthreads();
    #pragma unroll
    for (int jj = 0; jj < NJOB / 4; ++jj) {
      const int job = w * (NJOB / 4) + jj;
      if (job < 16) {
        GLL16(A + (size_t)(m0 + job * 8 + srow) * K + kk + scol, &As[job * 8][0]);
      } else {
        const int j2 = job - 16;
        GLL16(Bp + (size_t)(n0 + j2 * 8 + srow) * K + kk + scol, &Bs[j2 * 8][0]);
      }
    }
    __syncthreads();
    #pragma unroll
    for (int h = 0; h < 2; ++h) {
      const int ck = h ? ck1 : ck0;
      v8s af[4], bf[NFR];
      #pragma unroll
      for (int mt = 0; mt < 4; ++mt) af[mt] = *(const v8s*)(Asf + (wm + mt * 16 + l15) * 64 + ck);
      #pragma unroll
      for (int nt = 0; nt < NFR; ++nt) bf[nt] = *(const v8s*)(Bsf + (wn + nt * 16 + l15) * 64 + ck);
      #pragma unroll
      for (int mt = 0; mt < 4; ++mt)
        #pragma unroll
        for (int nt = 0; nt < NFR; ++nt)
          acc[mt][nt] = MFMA16(af[mt], bf[nt], acc[mt][nt]);
    }
  }

  if (QKV) {
    const int bh8 = b * 8;
    const float cs = 0.18033688011112042f;   // 0.125 * log2(e), folded into q
    #pragma unroll
    for (int mt = 0; mt < 4; ++mt) {
      const int m4 = m0 + wm + mt * 16 + quad * 4;
      const int h = m4 / 192;
      const int rr = m4 - h * 192;
      const int part = rr >> 6;                          // 0=q 1=k 2=v
      const int ch = rr & 63;
      const float b0 = bias[m4], b1 = bias[m4 + 1], b2 = bias[m4 + 2], b3 = bias[m4 + 3];
      #pragma unroll
      for (int nt = 0; nt < NFR; ++nt) {
        const int n = n0 + wn + nt * 16 + l15;
        v4f a = acc[mt][nt];
        const float v0 = a[0] + b0, v1 = a[1] + b1, v2 = a[2] + b2, v3 = a[3] + b3;
        if (part == 0) {
          ushort4 st4;
          st4.x = f2bf(v0 * cs); st4.y = f2bf(v1 * cs);
          st4.z = f2bf(v2 * cs); st4.w = f2bf(v3 * cs);
          *(ushort4*)(qT + ((size_t)(bh8 + h) * 1024 + n) * 64 + ch) = st4;
        } else if (part == 1) {
          ushort4 st4;
          st4.x = f2bf(v0); st4.y = f2bf(v1); st4.z = f2bf(v2); st4.w = f2bf(v3);
          *(ushort4*)(kT + ((size_t)(bh8 + h) * 1024 + n) * 64 + ch) = st4;
        } else {
          unsigned short* dp = vO + ((size_t)(bh8 + h) * 64 + ch) * 1024 + n;
          dp[0] = f2bf(v0); dp[1024] = f2bf(v1); dp[2048] = f2bf(v2); dp[3072] = f2bf(v3);
        }
      }
    }
  } else {
    #pragma unroll
    for (int mt = 0; mt < 4; ++mt) {
      const int m4 = m0 + wm + mt * 16 + quad * 4;
      const float b0 = bias[m4], b1 = bias[m4 + 1], b2 = bias[m4 + 2], b3 = bias[m4 + 3];
      #pragma unroll
      for (int nt = 0; nt < NFR; ++nt) {
        const int n = n0 + wn + nt * 16 + l15;
        const size_t i0 = ((size_t)b * 512 + m4) * 1024 + n;
        outf[i0]        = xres[i0]        + acc[mt][nt][0] + b0;
        outf[i0 + 1024] = xres[i0 + 1024] + acc[mt][nt][1] + b1;
        outf[i0 + 2048] = xres[i0 + 2048] + acc[mt][nt][2] + b2;
        outf[i0 + 3072] = xres[i0 + 3072] + acc[mt][nt][3] + b3;
      }
    }
  }
}

// ---------------- Flash attention: 256-thr, 128q/block, 128-s K/V tiles --------------
// qT/kT: [bh][1024][64] bf16 (q pre-scaled by 0.125*log2e); v: [bh][64][1024] bf16.
// grid = (bh, t): ID = bh + 64*t -> a head's t-blocks share an XCD (L2 K/V reuse).
// 128-s tiles halve the barrier count (8 drains) vs 64-s; 64KB LDS, Q staged
// through Ks[0] then held in registers. 2 blocks/CU (grid-limited, same as r6).
__global__ __launch_bounds__(256) void attn_kernel(const unsigned short* __restrict__ qT,
                                                   const unsigned short* __restrict__ kT,
                                                   const unsigned short* __restrict__ vv,
                                                   unsigned short* __restrict__ aT) {
  const int bh = blockIdx.x;
  const int t0 = blockIdx.y * 128;
  const unsigned short* qb = qT + (size_t)bh * 1024 * 64;
  const unsigned short* kb = kT + (size_t)bh * 1024 * 64;
  const unsigned short* vb = vv + (size_t)bh * 64 * 1024;

  __shared__ __align__(16) unsigned short Ks[2][128][64];    // 32KB [buf][s][k]
  __shared__ __align__(16) unsigned short Vs[2][2][64][64];  // 32KB [buf][s-half][c][s64]

  const int tid = threadIdx.x, w = tid >> 6, lane = tid & 63;
  const int quad = lane >> 4, l15 = lane & 15;
  const int srow = lane >> 3;
  const int scol = ((lane & 7) ^ srow) * 8;
  const int ck0 = ((quad ^ (l15 & 7)) * 8);
  const int ck1 = ck0 ^ 32;

  // ---- stage Q (128 rows) through Ks[0], read frags, release buffer ----
  #pragma unroll
  for (int jj = 0; jj < 4; ++jj) {
    const int seg = w * 4 + jj;              // 16 segs of 8 rows
    GLL16(qb + (size_t)(t0 + seg * 8 + srow) * 64 + scol, &Ks[0][seg * 8][0]);
  }
  __syncthreads();
  v8s qf[2][2];
  #pragma unroll
  for (int tg = 0; tg < 2; ++tg) {
    qf[tg][0] = *(const v8s*)(&Ks[0][0][0] + (w * 32 + tg * 16 + l15) * 64 + ck0);
    qf[tg][1] = *(const v8s*)(&Ks[0][0][0] + (w * 32 + tg * 16 + l15) * 64 + ck1);
  }
  __syncthreads();   // all waves done reading Q before Ks[0] is overwritten

  // ---- stage K/V tile 0 (128 s): 32 jobs of 8 rows, 8 per wave ----
  #pragma unroll
  for (int jj = 0; jj < 8; ++jj) {
    const int j = w * 8 + jj;
    if (j < 16) {
      GLL16(kb + (size_t)(j * 8 + srow) * 64 + scol, &Ks[0][j * 8][0]);
    } else {
      const int j2 = j - 16, hf = j2 >> 3, cg = (j2 & 7) * 8;
      GLL16(vb + (size_t)(cg + srow) * 1024 + hf * 64 + scol, &Vs[0][hf][cg][0]);
    }
  }

  v4f o[2][4];
  #pragma unroll
  for (int tg = 0; tg < 2; ++tg)
    #pragma unroll
    for (int i = 0; i < 4; ++i) o[tg][i] = (v4f){0.f, 0.f, 0.f, 0.f};
  float lsum[2] = {0.f, 0.f};

  // V B-frag (16x16x16) address pieces: row = nc*16+l15, s = st*16 + quad*4 + i
  const int vq4 = (quad & 1) * 4;          // within-chunk short offset
  const int vqh = quad >> 1;               // chunk parity from quad

  for (int it = 0; it < 8; ++it) {
    __syncthreads();          // tile(it) resident (drains prefetch issued last iter)
    if (it + 1 < 8) {         // prefetch tile it+1 before compute of tile it
      const int s1 = (it + 1) * 128, bp1 = (it + 1) & 1;
      #pragma unroll
      for (int jj = 0; jj < 8; ++jj) {
        const int j = w * 8 + jj;
        if (j < 16) {
          GLL16(kb + (size_t)(s1 + j * 8 + srow) * 64 + scol, &Ks[bp1][j * 8][0]);
        } else {
          const int j2 = j - 16, hf = j2 >> 3, cg = (j2 & 7) * 8;
          GLL16(vb + (size_t)(cg + srow) * 1024 + s1 + hf * 64 + scol,
                &Vs[bp1][hf][cg][0]);
        }
      }
    }
    const int buf = it & 1;

    #pragma unroll
    for (int hf = 0; hf < 2; ++hf) {
      const unsigned short* Kb = &Ks[buf][hf * 64][0];
      const unsigned short* Vb = &Vs[buf][hf][0][0];

      // S^T(64s x 32t) = K * Q^T ; sa[tg][st]: rows s = st*16+quad*4+r, col t = l15
      v4f sa[2][4];
      #pragma unroll
      for (int st = 0; st < 4; ++st) {
        v8s k0 = *(const v8s*)(Kb + (st * 16 + l15) * 64 + ck0);
        v8s k1 = *(const v8s*)(Kb + (st * 16 + l15) * 64 + ck1);
        #pragma unroll
        for (int tg = 0; tg < 2; ++tg) {
          v4f z = (v4f){0.f, 0.f, 0.f, 0.f};
          z = MFMA16(k0, qf[tg][0], z);
          sa[tg][st] = MFMA16(k1, qf[tg][1], z);
        }
      }

      // softmax without max subtraction (scores bounded; scale folded into q).
      union { v4s v; unsigned u[2]; } pa[2][4];
      #pragma unroll
      for (int tg = 0; tg < 2; ++tg) {
        float rsum = 0.f;
        #pragma unroll
        for (int st = 0; st < 4; ++st) {
          float p0 = exp2n(sa[tg][st][0]);
          float p1 = exp2n(sa[tg][st][1]);
          float p2 = exp2n(sa[tg][st][2]);
          float p3 = exp2n(sa[tg][st][3]);
          rsum += (p0 + p1) + (p2 + p3);
          pa[tg][st].u[0] = packbf2(p0, p1);
          pa[tg][st].u[1] = packbf2(p2, p3);
        }
        lsum[tg] += rsum;
      }

      // O(32t x 64c) += P * V ; B-frag V[s=st*16+quad*4+i][c=nc*16+l15] via ds_read_b64
      #pragma unroll
      for (int nc = 0; nc < 4; ++nc) {
        const int row = nc * 16 + l15;
        const unsigned short* vrow = Vb + row * 64 + vq4;
        const int rx = row & 7;
        #pragma unroll
        for (int st = 0; st < 4; ++st) {
          v4s vb4 = *(const v4s*)(vrow + ((st * 2 + vqh) ^ rx) * 8);
          o[0][nc] = MFMA16K16(pa[0][st].v, vb4, o[0][nc]);
          o[1][nc] = MFMA16K16(pa[1][st].v, vb4, o[1][nc]);
        }
      }
    }
  }

  // final l reduce across quads; write aT[b][t][h*64+c] = O[t][c] / l(t)
  const int b = bh >> 3, h = bh & 7;
  #pragma unroll
  for (int tg = 0; tg < 2; ++tg) {
    lsum[tg] += __shfl_xor(lsum[tg], 16);
    lsum[tg] += __shfl_xor(lsum[tg], 32);
  }
  #pragma unroll
  for (int tg = 0; tg < 2; ++tg) {
    float rl[4];
    #pragma unroll
    for (int r = 0; r < 4; ++r) rl[r] = 1.0f / __shfl(lsum[tg], quad * 4 + r);
    #pragma unroll
    for (int nc = 0; nc < 4; ++nc)
      #pragma unroll
      for (int r = 0; r < 4; ++r) {
        aT[((size_t)b * 1024 + t0 + w * 32 + tg * 16 + quad * 4 + r) * 512 +
           h * 64 + nc * 16 + l15] = f2bf(o[tg][nc][r] * rl[r]);
      }
  }
}

extern "C" void kernel_launch(void* const* d_in, const int* in_sizes, int n_in,
                              void* d_out, int out_size, void* d_ws, size_t ws_size,
                              hipStream_t stream) {
  const float* x    = (const float*)d_in[0];
  const float* gsc  = (const float*)d_in[1];
  const float* gbi  = (const float*)d_in[2];
  const float* qkvw = (const float*)d_in[3];
  const float* qkvb = (const float*)d_in[4];
  const float* pjw  = (const float*)d_in[5];
  const float* pjb  = (const float*)d_in[6];
  float* out = (float*)d_out;

  unsigned short* ws  = (unsigned short*)d_ws;
  unsigned short* qw  = ws;                   //  786432  qkv weights bf16
  unsigned short* pw  = qw + 786432;          //  262144  proj weights bf16
  float2* stats = (float2*)(pw + 262144);     //  256 float2 = 1024 shorts
  unsigned short* xnT = pw + 262144 + 1024;   // 4194304  [b][l][c]
  unsigned short* qT  = xnT + 4194304;        // 4194304  [bh][l][64]
  unsigned short* kT  = qT + 4194304;         // 4194304  [bh][l][64]
  unsigned short* vv  = kT + 4194304;         // 4194304  [bh][64][l]
  unsigned short* aT  = vv + 4194304;         // 4194304  [b][l][c]
  // total ~44.04 MB

  cvt_gn_kernel<<<dim3(1280), dim3(256), 0, stream>>>(qkvw, qw, pjw, pw, 196608, 65536,
                                                      x, stats);
  gnt_kernel<<<dim3(16, 8, 8), dim3(256), 0, stream>>>(x, stats, gsc, gbi, xnT);
  gemm_kernel<true, 128><<<dim3(8, 12, 8), dim3(256), 0, stream>>>(
      qw, xnT, qkvb, nullptr, nullptr, qT, kT, vv);
  attn_kernel<<<dim3(64, 8), dim3(256), 0, stream>>>(qT, kT, vv, aT);
  gemm_kernel<false, 64><<<dim3(16, 4, 8), dim3(256), 0, stream>>>(
      pw, aT, pjb, x, out, nullptr, nullptr, nullptr);
}

// Round 9
// 147.998 us; speedup vs baseline: 1.0229x; 1.0087x over previous
//
#include <hip/hip_runtime.h>
#include <hip/hip_bf16.h>

typedef __attribute__((ext_vector_type(8))) short v8s;            // 8 x bf16 (4 VGPRs) MFMA A/B (K=32)
typedef __attribute__((ext_vector_type(4))) short v4s;            // 4 x bf16 (2 VGPRs) MFMA A/B (K=16)
typedef __attribute__((ext_vector_type(8))) unsigned short u16x8;
typedef __attribute__((ext_vector_type(4))) float v4f;            // MFMA C/D

#define MFMA16(a, b, c) __builtin_amdgcn_mfma_f32_16x16x32_bf16((a), (b), (c), 0, 0, 0)

// K=16 bf16 MFMA: A-frag k = quad*4+j matches the 16x16 C-layout row granularity,
// so an S^T C-layout register block is directly a PV A-fragment (no cross-lane ops).
#if __has_builtin(__builtin_amdgcn_mfma_f32_16x16x16_bf16)
#define MFMA16K16(a, b, c) __builtin_amdgcn_mfma_f32_16x16x16_bf16((a), (b), (c), 0, 0, 0)
#elif __has_builtin(__builtin_amdgcn_mfma_f32_16x16x16bf16_1k)
#define MFMA16K16(a, b, c) __builtin_amdgcn_mfma_f32_16x16x16bf16_1k((a), (b), (c), 0, 0, 0)
#else
static __device__ __forceinline__ v4f mfma16k16_asm(v4s a, v4s b, v4f c) {
  v4f d;
  asm("v_mfma_f32_16x16x16_bf16 %0, %1, %2, %3" : "=v"(d) : "v"(a), "v"(b), "v"(c));
  return d;
}
#define MFMA16K16(a, b, c) mfma16k16_asm((a), (b), (c))
#endif

// async global->LDS, 16B per lane; LDS dest = wave-uniform base + lane*16
#define GLL16(g, l)                                                        \
  __builtin_amdgcn_global_load_lds(                                        \
      (const __attribute__((address_space(1))) unsigned int*)(g),          \
      (__attribute__((address_space(3))) unsigned int*)(l), 16, 0, 0)

// native v_exp_f32 (libm exp2f is a multi-op software expansion)
#if __has_builtin(__builtin_amdgcn_exp2f)
__device__ __forceinline__ float exp2n(float x) { return __builtin_amdgcn_exp2f(x); }
#else
__device__ __forceinline__ float exp2n(float x) {
  float r; asm("v_exp_f32 %0, %1" : "=v"(r) : "v"(x)); return r;
}
#endif

__device__ __forceinline__ unsigned short f2bf(float f) {
  union { float f; unsigned u; } v; v.f = f;
  unsigned r = v.u + 0x7fffu + ((v.u >> 16) & 1u);   // RNE
  return (unsigned short)(r >> 16);
}
// truncating pack of two f32 -> bf16x2 (lo in low half)
__device__ __forceinline__ unsigned packbf2(float lo, float hi) {
  union { float f; unsigned u; } a, b; a.f = lo; b.f = hi;
  return (a.u >> 16) | (b.u & 0xffff0000u);
}

// ---------------- fused: weight fp32->bf16 convert  +  GroupNorm stats ----------------
__global__ __launch_bounds__(256) void cvt_gn_kernel(const float* __restrict__ in0,
                                                     unsigned short* __restrict__ out0,
                                                     const float* __restrict__ in1,
                                                     unsigned short* __restrict__ out1,
                                                     int n0, int n1,
                                                     const float* __restrict__ x,
                                                     float2* __restrict__ stats) {
  if (blockIdx.x < 1024) {
    int i = blockIdx.x * 256 + threadIdx.x;
    const float* in; unsigned short* out;
    if (i < n0) { in = in0; out = out0; }
    else        { i -= n0; if (i >= n1) return; in = in1; out = out1; }
    float4 v = ((const float4*)in)[i];
    ushort4 o;
    o.x = f2bf(v.x); o.y = f2bf(v.y); o.z = f2bf(v.z); o.w = f2bf(v.w);
    ((ushort4*)out)[i] = o;
    return;
  }
  const int bg = blockIdx.x - 1024;            // 0..255
  const float4* xp4 = (const float4*)(x + (size_t)bg * 16 * 1024);
  float s = 0.f, ss = 0.f;
  for (int i = threadIdx.x; i < 4096; i += 256) {
    float4 v = xp4[i];
    s  += (v.x + v.y) + (v.z + v.w);
    ss += (v.x * v.x + v.y * v.y) + (v.z * v.z + v.w * v.w);
  }
  #pragma unroll
  for (int d = 1; d < 64; d <<= 1) { s += __shfl_xor(s, d); ss += __shfl_xor(ss, d); }
  __shared__ float red[2][4];
  const int w = threadIdx.x >> 6;
  if ((threadIdx.x & 63) == 0) { red[0][w] = s; red[1][w] = ss; }
  __syncthreads();
  if (threadIdx.x == 0) {
    s  = red[0][0] + red[0][1] + red[0][2] + red[0][3];
    ss = red[1][0] + red[1][1] + red[1][2] + red[1][3];
    const float mu  = s * (1.f / 16384.f);
    const float var = ss * (1.f / 16384.f) - mu * mu;
    stats[bg] = make_float2(mu, rsqrtf(var + 1e-5f));
  }
}

// ---------------- GroupNorm normalize + transpose: x[b][c][l] -> xnT[b][l][c] bf16 ----
__global__ __launch_bounds__(256) void gnt_kernel(const float* __restrict__ x,
                                                  const float2* __restrict__ stats,
                                                  const float* __restrict__ gsc,
                                                  const float* __restrict__ gbi,
                                                  unsigned short* __restrict__ xnT) {
  const int b = blockIdx.z, l0 = blockIdx.x * 64, c0 = blockIdx.y * 64;
  const float* sp = x + (size_t)b * 512 * 1024;
  unsigned short* dp = xnT + (size_t)b * 1024 * 512;
  __shared__ unsigned T[64][65];
  const int tid = threadIdx.x;
  const int rr = tid >> 3, c8 = (tid & 7) * 8;
  #pragma unroll
  for (int sw = 0; sw < 2; ++sw) {
    const int c = c0 + sw * 32 + rr;
    const float2 st = stats[b * 32 + (c >> 4)];
    const float sc = gsc[c] * st.y;
    const float bi = gbi[c] - st.x * sc;
    const float4* px = (const float4*)(sp + (size_t)c * 1024 + l0 + c8);
    float4 v0 = px[0], v1 = px[1];
    T[sw * 32 + rr][c8 + 0] = f2bf(v0.x * sc + bi);
    T[sw * 32 + rr][c8 + 1] = f2bf(v0.y * sc + bi);
    T[sw * 32 + rr][c8 + 2] = f2bf(v0.z * sc + bi);
    T[sw * 32 + rr][c8 + 3] = f2bf(v0.w * sc + bi);
    T[sw * 32 + rr][c8 + 4] = f2bf(v1.x * sc + bi);
    T[sw * 32 + rr][c8 + 5] = f2bf(v1.y * sc + bi);
    T[sw * 32 + rr][c8 + 6] = f2bf(v1.z * sc + bi);
    T[sw * 32 + rr][c8 + 7] = f2bf(v1.w * sc + bi);
  }
  __syncthreads();
  #pragma unroll
  for (int sw = 0; sw < 2; ++sw) {
    const int ll = sw * 32 + rr;
    u16x8 o;
    #pragma unroll
    for (int j = 0; j < 8; ++j) o[j] = (unsigned short)T[c8 + j][ll];
    *(u16x8*)(dp + (size_t)(l0 + ll) * 512 + c0 + c8) = o;
  }
}

// ---------------- 128xNT MFMA GEMM, BK=64, xor-swizzled 128B LDS rows ----------------
template <bool QKV, int NT>
__global__ __launch_bounds__(256) void gemm_kernel(
    const unsigned short* __restrict__ A,
    const unsigned short* __restrict__ BT,
    const float* __restrict__ bias,
    const float* __restrict__ xres,
    float* __restrict__ outf,
    unsigned short* __restrict__ qT,
    unsigned short* __restrict__ kT,
    unsigned short* __restrict__ vO) {
  constexpr int K = 512;
  constexpr int NFR = NT / 32;              // n-frags per wave
  constexpr int NJOB = 16 + NT / 8;         // staging jobs (A:16, B:NT/8)
  const int n0 = blockIdx.x * NT, m0 = blockIdx.y * 128, b = blockIdx.z;
  const unsigned short* Bp = BT + (size_t)b * 1024 * K;

  __shared__ __align__(16) unsigned short As[128][64];
  __shared__ __align__(16) unsigned short Bs[NT][64];

  const int tid = threadIdx.x, lane = tid & 63, w = tid >> 6;
  const int quad = lane >> 4, l15 = lane & 15;
  const int wm = (w >> 1) * 64, wn = (w & 1) * (NT / 2);
  const int srow = lane >> 3;
  const int scol = ((lane & 7) ^ srow) * 8;
  const int ck0 = ((quad ^ (l15 & 7)) * 8);
  const int ck1 = ck0 ^ 32;
  const unsigned short* Asf = &As[0][0];
  const unsigned short* Bsf = &Bs[0][0];

  v4f acc[4][NFR];
  #pragma unroll
  for (int i = 0; i < 4; ++i)
    #pragma unroll
    for (int j = 0; j < NFR; ++j) acc[i][j] = (v4f){0.f, 0.f, 0.f, 0.f};

  for (int kk = 0; kk < K; kk += 64) {
    __syncthreads();
    #pragma unroll
    for (int jj = 0; jj < NJOB / 4; ++jj) {
      const int job = w * (NJOB / 4) + jj;
      if (job < 16) {
        GLL16(A + (size_t)(m0 + job * 8 + srow) * K + kk + scol, &As[job * 8][0]);
      } else {
        const int j2 = job - 16;
        GLL16(Bp + (size_t)(n0 + j2 * 8 + srow) * K + kk + scol, &Bs[j2 * 8][0]);
      }
    }
    __syncthreads();
    #pragma unroll
    for (int h = 0; h < 2; ++h) {
      const int ck = h ? ck1 : ck0;
      v8s af[4], bf[NFR];
      #pragma unroll
      for (int mt = 0; mt < 4; ++mt) af[mt] = *(const v8s*)(Asf + (wm + mt * 16 + l15) * 64 + ck);
      #pragma unroll
      for (int nt = 0; nt < NFR; ++nt) bf[nt] = *(const v8s*)(Bsf + (wn + nt * 16 + l15) * 64 + ck);
      #pragma unroll
      for (int mt = 0; mt < 4; ++mt)
        #pragma unroll
        for (int nt = 0; nt < NFR; ++nt)
          acc[mt][nt] = MFMA16(af[mt], bf[nt], acc[mt][nt]);
    }
  }

  if (QKV) {
    const int bh8 = b * 8;
    const float cs = 0.18033688011112042f;   // 0.125 * log2(e), folded into q
    #pragma unroll
    for (int mt = 0; mt < 4; ++mt) {
      const int m4 = m0 + wm + mt * 16 + quad * 4;
      const int h = m4 / 192;
      const int rr = m4 - h * 192;
      const int part = rr >> 6;                          // 0=q 1=k 2=v
      const int ch = rr & 63;
      const float b0 = bias[m4], b1 = bias[m4 + 1], b2 = bias[m4 + 2], b3 = bias[m4 + 3];
      #pragma unroll
      for (int nt = 0; nt < NFR; ++nt) {
        const int n = n0 + wn + nt * 16 + l15;
        v4f a = acc[mt][nt];
        const float v0 = a[0] + b0, v1 = a[1] + b1, v2 = a[2] + b2, v3 = a[3] + b3;
        if (part == 0) {
          ushort4 st4;
          st4.x = f2bf(v0 * cs); st4.y = f2bf(v1 * cs);
          st4.z = f2bf(v2 * cs); st4.w = f2bf(v3 * cs);
          *(ushort4*)(qT + ((size_t)(bh8 + h) * 1024 + n) * 64 + ch) = st4;
        } else if (part == 1) {
          ushort4 st4;
          st4.x = f2bf(v0); st4.y = f2bf(v1); st4.z = f2bf(v2); st4.w = f2bf(v3);
          *(ushort4*)(kT + ((size_t)(bh8 + h) * 1024 + n) * 64 + ch) = st4;
        } else {
          unsigned short* dp = vO + ((size_t)(bh8 + h) * 64 + ch) * 1024 + n;
          dp[0] = f2bf(v0); dp[1024] = f2bf(v1); dp[2048] = f2bf(v2); dp[3072] = f2bf(v3);
        }
      }
    }
  } else {
    #pragma unroll
    for (int mt = 0; mt < 4; ++mt) {
      const int m4 = m0 + wm + mt * 16 + quad * 4;
      const float b0 = bias[m4], b1 = bias[m4 + 1], b2 = bias[m4 + 2], b3 = bias[m4 + 3];
      #pragma unroll
      for (int nt = 0; nt < NFR; ++nt) {
        const int n = n0 + wn + nt * 16 + l15;
        const size_t i0 = ((size_t)b * 512 + m4) * 1024 + n;
        outf[i0]        = xres[i0]        + acc[mt][nt][0] + b0;
        outf[i0 + 1024] = xres[i0 + 1024] + acc[mt][nt][1] + b1;
        outf[i0 + 2048] = xres[i0 + 2048] + acc[mt][nt][2] + b2;
        outf[i0 + 3072] = xres[i0 + 3072] + acc[mt][nt][3] + b3;
      }
    }
  }
}

// ---------------- Flash attention: 256q/block, 64 q/wave, 128-s K/V tiles ------------
// qT/kT: [bh][1024][64] bf16 (q pre-scaled by 0.125*log2e); v: [bh][64][1024] bf16.
// grid = (bh, t): ID = bh + 64*t -> a head's t-blocks share an XCD (L2 K/V reuse).
// 64 q/wave: K/V fragments hoisted to registers once per subtile and reused across
// FOUR 16-query groups -> per-CU DS-pipe traffic (the measured wall) halves vs r8.
// 1 block/CU, 1 wave/SIMD: VGPR budget 512 -> ~210 VGPRs is safe.
__global__ __launch_bounds__(256) void attn_kernel(const unsigned short* __restrict__ qT,
                                                   const unsigned short* __restrict__ kT,
                                                   const unsigned short* __restrict__ vv,
                                                   unsigned short* __restrict__ aT) {
  const int bh = blockIdx.x;
  const int t0 = blockIdx.y * 256;
  const unsigned short* qb = qT + (size_t)bh * 1024 * 64;
  const unsigned short* kb = kT + (size_t)bh * 1024 * 64;
  const unsigned short* vb = vv + (size_t)bh * 64 * 1024;

  __shared__ __align__(16) unsigned short Ks[2][128][64];    // 32KB [buf][s][k]
  __shared__ __align__(16) unsigned short Vs[2][2][64][64];  // 32KB [buf][s-half][c][s64]

  const int tid = threadIdx.x, w = tid >> 6, lane = tid & 63;
  const int quad = lane >> 4, l15 = lane & 15;
  const int srow = lane >> 3;
  const int scol = ((lane & 7) ^ srow) * 8;
  const int ck0 = ((quad ^ (l15 & 7)) * 8);
  const int ck1 = ck0 ^ 32;

  // ---- stage Q (256 rows) through Ks[0..1] (exactly 256 rows), read frags ----
  #pragma unroll
  for (int jj = 0; jj < 8; ++jj) {
    const int seg = w * 8 + jj;              // 32 segs of 8 rows
    GLL16(qb + (size_t)(t0 + seg * 8 + srow) * 64 + scol, &Ks[0][0][0] + seg * 8 * 64);
  }
  __syncthreads();
  v8s qf[4][2];
  #pragma unroll
  for (int tg = 0; tg < 4; ++tg) {
    const int row = w * 64 + tg * 16 + l15;  // row&7 == l15&7 (swizzle-consistent)
    qf[tg][0] = *(const v8s*)(&Ks[0][0][0] + row * 64 + ck0);
    qf[tg][1] = *(const v8s*)(&Ks[0][0][0] + row * 64 + ck1);
  }
  __syncthreads();   // all waves done reading Q before Ks is overwritten

  // ---- stage K/V tile 0 (128 s): 32 jobs of 8 rows, 8 per wave ----
  #pragma unroll
  for (int jj = 0; jj < 8; ++jj) {
    const int j = w * 8 + jj;
    if (j < 16) {
      GLL16(kb + (size_t)(j * 8 + srow) * 64 + scol, &Ks[0][j * 8][0]);
    } else {
      const int j2 = j - 16, hf = j2 >> 3, cg = (j2 & 7) * 8;
      GLL16(vb + (size_t)(cg + srow) * 1024 + hf * 64 + scol, &Vs[0][hf][cg][0]);
    }
  }

  v4f o[4][4];
  #pragma unroll
  for (int tg = 0; tg < 4; ++tg)
    #pragma unroll
    for (int i = 0; i < 4; ++i) o[tg][i] = (v4f){0.f, 0.f, 0.f, 0.f};
  float lsum[4] = {0.f, 0.f, 0.f, 0.f};

  // V B-frag (16x16x16) address pieces: row = nc*16+l15, s = st*16 + quad*4 + i
  const int vq4 = (quad & 1) * 4;          // within-chunk short offset
  const int vqh = quad >> 1;               // chunk parity from quad

  for (int it = 0; it < 8; ++it) {
    __syncthreads();          // tile(it) resident (drains prefetch issued last iter)
    if (it + 1 < 8) {         // prefetch tile it+1 before compute of tile it
      const int s1 = (it + 1) * 128, bp1 = (it + 1) & 1;
      #pragma unroll
      for (int jj = 0; jj < 8; ++jj) {
        const int j = w * 8 + jj;
        if (j < 16) {
          GLL16(kb + (size_t)(s1 + j * 8 + srow) * 64 + scol, &Ks[bp1][j * 8][0]);
        } else {
          const int j2 = j - 16, hf = j2 >> 3, cg = (j2 & 7) * 8;
          GLL16(vb + (size_t)(cg + srow) * 1024 + s1 + hf * 64 + scol,
                &Vs[bp1][hf][cg][0]);
        }
      }
    }
    const int buf = it & 1;

    #pragma unroll
    for (int hf = 0; hf < 2; ++hf) {
      const unsigned short* Kb = &Ks[buf][hf * 64][0];
      const unsigned short* Vb = &Vs[buf][hf][0][0];

      // hoist K and V fragments once; reuse across all 4 query groups
      v8s kf[4][2];
      #pragma unroll
      for (int st = 0; st < 4; ++st) {
        kf[st][0] = *(const v8s*)(Kb + (st * 16 + l15) * 64 + ck0);
        kf[st][1] = *(const v8s*)(Kb + (st * 16 + l15) * 64 + ck1);
      }
      v4s vfr[4][4];
      #pragma unroll
      for (int nc = 0; nc < 4; ++nc) {
        const int row = nc * 16 + l15;
        const unsigned short* vrow = Vb + row * 64 + vq4;
        const int rx = row & 7;
        #pragma unroll
        for (int st = 0; st < 4; ++st)
          vfr[nc][st] = *(const v4s*)(vrow + ((st * 2 + vqh) ^ rx) * 8);
      }

      #pragma unroll
      for (int tg = 0; tg < 4; ++tg) {
        // S^T(64s x 16t) = K * Q^T ; sa[st]: rows s = st*16+quad*4+r, col t = l15
        v4f sa[4];
        #pragma unroll
        for (int st = 0; st < 4; ++st) {
          v4f z = (v4f){0.f, 0.f, 0.f, 0.f};
          z = MFMA16(kf[st][0], qf[tg][0], z);
          sa[st] = MFMA16(kf[st][1], qf[tg][1], z);
        }
        // softmax without max subtraction; P in C-layout == K=16 A-fragment
        union { v4s v; unsigned u[2]; } pa[4];
        float rsum = 0.f;
        #pragma unroll
        for (int st = 0; st < 4; ++st) {
          float p0 = exp2n(sa[st][0]);
          float p1 = exp2n(sa[st][1]);
          float p2 = exp2n(sa[st][2]);
          float p3 = exp2n(sa[st][3]);
          rsum += (p0 + p1) + (p2 + p3);
          pa[st].u[0] = packbf2(p0, p1);
          pa[st].u[1] = packbf2(p2, p3);
        }
        lsum[tg] += rsum;
        // O(16t x 64c) += P * V
        #pragma unroll
        for (int nc = 0; nc < 4; ++nc)
          #pragma unroll
          for (int st = 0; st < 4; ++st)
            o[tg][nc] = MFMA16K16(pa[st].v, vfr[nc][st], o[tg][nc]);
      }
    }
  }

  // final l reduce across quads; write aT[b][t][h*64+c] = O[t][c] / l(t)
  const int b = bh >> 3, h = bh & 7;
  #pragma unroll
  for (int tg = 0; tg < 4; ++tg) {
    lsum[tg] += __shfl_xor(lsum[tg], 16);
    lsum[tg] += __shfl_xor(lsum[tg], 32);
  }
  #pragma unroll
  for (int tg = 0; tg < 4; ++tg) {
    float rl[4];
    #pragma unroll
    for (int r = 0; r < 4; ++r) rl[r] = 1.0f / __shfl(lsum[tg], quad * 4 + r);
    #pragma unroll
    for (int nc = 0; nc < 4; ++nc)
      #pragma unroll
      for (int r = 0; r < 4; ++r) {
        aT[((size_t)b * 1024 + t0 + w * 64 + tg * 16 + quad * 4 + r) * 512 +
           h * 64 + nc * 16 + l15] = f2bf(o[tg][nc][r] * rl[r]);
      }
  }
}

extern "C" void kernel_launch(void* const* d_in, const int* in_sizes, int n_in,
                              void* d_out, int out_size, void* d_ws, size_t ws_size,
                              hipStream_t stream) {
  const float* x    = (const float*)d_in[0];
  const float* gsc  = (const float*)d_in[1];
  const float* gbi  = (const float*)d_in[2];
  const float* qkvw = (const float*)d_in[3];
  const float* qkvb = (const float*)d_in[4];
  const float* pjw  = (const float*)d_in[5];
  const float* pjb  = (const float*)d_in[6];
  float* out = (float*)d_out;

  unsigned short* ws  = (unsigned short*)d_ws;
  unsigned short* qw  = ws;                   //  786432  qkv weights bf16
  unsigned short* pw  = qw + 786432;          //  262144  proj weights bf16
  float2* stats = (float2*)(pw + 262144);     //  256 float2 = 1024 shorts
  unsigned short* xnT = pw + 262144 + 1024;   // 4194304  [b][l][c]
  unsigned short* qT  = xnT + 4194304;        // 4194304  [bh][l][64]
  unsigned short* kT  = qT + 4194304;         // 4194304  [bh][l][64]
  unsigned short* vv  = kT + 4194304;         // 4194304  [bh][64][l]
  unsigned short* aT  = vv + 4194304;         // 4194304  [b][l][c]
  // total ~44.04 MB

  cvt_gn_kernel<<<dim3(1280), dim3(256), 0, stream>>>(qkvw, qw, pjw, pw, 196608, 65536,
                                                      x, stats);
  gnt_kernel<<<dim3(16, 8, 8), dim3(256), 0, stream>>>(x, stats, gsc, gbi, xnT);
  gemm_kernel<true, 128><<<dim3(8, 12, 8), dim3(256), 0, stream>>>(
      qw, xnT, qkvb, nullptr, nullptr, qT, kT, vv);
  attn_kernel<<<dim3(64, 4), dim3(256), 0, stream>>>(qT, kT, vv, aT);
  gemm_kernel<false, 64><<<dim3(16, 4, 8), dim3(256), 0, stream>>>(
      pw, aT, pjb, x, out, nullptr, nullptr, nullptr);
}